// Round 5
// baseline (171.439 us; speedup 1.0000x reference)
//
#include <hip/hip_runtime.h>
#include <math.h>

#define BQ 4096
#define DD 256
#define NNEG 32768

typedef __bf16 bf16x8 __attribute__((ext_vector_type(8)));
typedef float f32x4 __attribute__((ext_vector_type(4)));

// ws layout (floats):
//   diag[4096] | rpart[64*4096] | cpart[64*4096] | npart[32768]
// Every slot is written every call (no zero-init needed; poison-proof).

__device__ __forceinline__ float get_inv_tau(const float* __restrict__ lt) {
  float tau = __expf(lt[0]);
  tau = fminf(fmaxf(tau, 1e-4f), 1.0f);
  return 1.0f / tau;
}

__device__ __forceinline__ unsigned int f2bf(float f) {
  unsigned int u = __float_as_uint(f);
  u += 0x7FFFu + ((u >> 16) & 1u);  // RNE
  return u >> 16;
}
__device__ __forceinline__ unsigned int pack2(float a, float b) {
  return f2bf(a) | (f2bf(b) << 16);
}

// ---------------- fused sim + neg, dependency-free ----------------
// blocks [0,1024): sim 128x128 tile, 4 waves (2x2), BK=64 single LDS buffer,
//   inline f32->bf16 reg-staging, XOR-swizzled LDS (write+read), partial-sum
//   epilogue (no atomics).
// blocks [1024,2048): negatives; each block scans counts itself (no dep),
//   8 lanes per negative, npart[j] = exp(q_ow . n_j / tau).
__global__ __launch_bounds__(256) void simneg_kernel(
    const float* __restrict__ q, const float* __restrict__ p,
    const float* __restrict__ n_emb, const int* __restrict__ counts,
    const float* __restrict__ logtau,
    float* __restrict__ diag, float* __restrict__ rpart,
    float* __restrict__ cpart, float* __restrict__ npart) {
  __shared__ ushort As[2][8192];  // 32KB: [0]=A tile, [1]=B tile; neg: int P[4096]
  __shared__ int wtot[4];

  const int tid = threadIdx.x;
  const int bid = (int)blockIdx.x;
  const float inv_tau = get_inv_tau(logtau);

  if (bid >= 1024) {
    // ---------------- negatives ----------------
    int* P = (int*)&As[0][0];  // inclusive prefix of counts
    const int lane = tid & 63, wid = tid >> 6;
    int cl[16];
    int s = 0;
#pragma unroll
    for (int i = 0; i < 4; ++i) {
      const int4 cc = reinterpret_cast<const int4*>(counts)[tid * 4 + i];
      cl[4 * i + 0] = cc.x; cl[4 * i + 1] = cc.y;
      cl[4 * i + 2] = cc.z; cl[4 * i + 3] = cc.w;
    }
    int run = 0;
#pragma unroll
    for (int k = 0; k < 16; ++k) { run += cl[k]; cl[k] = run; }
    s = run;
    int x = s;
#pragma unroll
    for (int off = 1; off < 64; off <<= 1) {
      const int v = __shfl_up(x, off);
      if (lane >= off) x += v;
    }
    if (lane == 63) wtot[wid] = x;
    __syncthreads();
    int base = 0;
    for (int w = 0; w < wid; ++w) base += wtot[w];
    base += x - s;  // exclusive prefix for query 16*tid
#pragma unroll
    for (int k = 0; k < 16; ++k) P[16 * tid + k] = base + cl[k];
    __syncthreads();

    const int j = (bid - 1024) * 32 + (tid >> 3);  // negative id
    const int sl = tid & 7;
    // owner = first i with P[i] > j
    int lo = 0, hi = 4095;
    while (lo < hi) {
      const int mid = (lo + hi) >> 1;
      if (P[mid] > j) hi = mid; else lo = mid + 1;
    }
    const int ow = lo;
    const float4* nrow = reinterpret_cast<const float4*>(n_emb + (size_t)j * DD);
    const float4* qrow = reinterpret_cast<const float4*>(q + (size_t)ow * DD);
    float d0 = 0.f, d1 = 0.f;
#pragma unroll
    for (int t2 = 0; t2 < 8; t2 += 2) {
      const float4 n0 = nrow[sl + 8 * t2];
      const float4 q0 = qrow[sl + 8 * t2];
      const float4 n1 = nrow[sl + 8 * (t2 + 1)];
      const float4 q1 = qrow[sl + 8 * (t2 + 1)];
      d0 += q0.x * n0.x + q0.y * n0.y + q0.z * n0.z + q0.w * n0.w;
      d1 += q1.x * n1.x + q1.y * n1.y + q1.z * n1.z + q1.w * n1.w;
    }
    float d = d0 + d1;
    d += __shfl_xor(d, 1);
    d += __shfl_xor(d, 2);
    d += __shfl_xor(d, 4);
    if (sl == 0) npart[j] = __expf(d * inv_tau);
    return;
  }

  // ---------------- sim tile ----------------
  const int lane = tid & 63;
  const int wv = tid >> 6;
  const int wr = wv >> 1, wc = wv & 1;
  const int lrow = lane >> 4;   // 0..3
  const int lcol = lane & 15;   // 0..15

  // XCD-aware swizzle (1024 sim blocks, bijective: 8*128)
  const int swz = (bid & 7) * 128 + (bid >> 3);
  const int bx = swz & 31, by = swz >> 5;
  const int brow = by * 128, bcol = bx * 128;

  // staging map: thread stages row ra, col-half ca (32 f32 each for A and B)
  const int ra = tid & 127, ca = tid >> 7;
  char* Ab = (char*)&As[0][0];
  char* Bb = (char*)&As[1][0];
  char* awr = Ab + ra * 128;
  char* bwr = Bb + ra * 128;
  const int wswz = (ra & 7) << 4;  // write-side XOR (bits 4-6 of byte-in-row)

  f32x4 acc[4][4];
#pragma unroll
  for (int i = 0; i < 4; ++i)
#pragma unroll
    for (int j = 0; j < 4; ++j) acc[i][j] = (f32x4){0.f, 0.f, 0.f, 0.f};

  float4 sa[8], sb[8];
#define LOAD(k0)                                                                 \
  {                                                                              \
    const float4* qs = (const float4*)(q + (size_t)(brow + ra) * DD + (k0) + ca * 32); \
    const float4* ps = (const float4*)(p + (size_t)(bcol + ra) * DD + (k0) + ca * 32); \
    _Pragma("unroll") for (int u = 0; u < 8; ++u) { sa[u] = qs[u]; sb[u] = ps[u]; } \
  }

#define WRITE()                                                                  \
  {                                                                              \
    _Pragma("unroll") for (int u = 0; u < 4; ++u) {                              \
      uint4 w;                                                                   \
      w.x = pack2(sa[2 * u].x, sa[2 * u].y);                                     \
      w.y = pack2(sa[2 * u].z, sa[2 * u].w);                                     \
      w.z = pack2(sa[2 * u + 1].x, sa[2 * u + 1].y);                             \
      w.w = pack2(sa[2 * u + 1].z, sa[2 * u + 1].w);                             \
      *(uint4*)(awr + ((ca * 64 + u * 16) ^ wswz)) = w;                          \
      uint4 v2;                                                                  \
      v2.x = pack2(sb[2 * u].x, sb[2 * u].y);                                    \
      v2.y = pack2(sb[2 * u].z, sb[2 * u].w);                                    \
      v2.z = pack2(sb[2 * u + 1].x, sb[2 * u + 1].y);                            \
      v2.w = pack2(sb[2 * u + 1].z, sb[2 * u + 1].w);                            \
      *(uint4*)(bwr + ((ca * 64 + u * 16) ^ wswz)) = v2;                         \
    }                                                                            \
  }

  // read-side fragment bases (XOR term identical for A and B: (lcol&7)<<4)
  const int arow = wr * 64 + lcol;
  const int brow_f = wc * 64 + lcol;
  const int rswz = (lcol & 7) << 4;
  const char* ard = Ab + arow * 128;
  const char* brd = Bb + brow_f * 128;

  LOAD(0);
#pragma unroll
  for (int t = 0; t < 4; ++t) {
    if (t > 0) __syncthreads();   // previous tile's compute done
    WRITE();                      // (compiler waits vmcnt for sa/sb)
    __syncthreads();              // tile visible
    if (t < 3) LOAD((t + 1) * 64);  // issue-early: overlaps compute (T14)
#pragma unroll
    for (int sub = 0; sub < 2; ++sub) {
      const int rb = (sub * 64 + lrow * 16) ^ rswz;
      bf16x8 af[4], bf[4];
#pragma unroll
      for (int m = 0; m < 4; ++m) af[m] = *(const bf16x8*)(ard + m * 2048 + rb);
#pragma unroll
      for (int n = 0; n < 4; ++n) bf[n] = *(const bf16x8*)(brd + n * 2048 + rb);
#pragma unroll
      for (int m = 0; m < 4; ++m)
#pragma unroll
        for (int n = 0; n < 4; ++n)
          acc[m][n] = __builtin_amdgcn_mfma_f32_16x16x32_bf16(af[m], bf[n], acc[m][n], 0, 0, 0);
    }
  }
#undef LOAD
#undef WRITE

  // epilogue: exp + partial row/col sums (plain stores, unique writer per slot)
  const int arow0 = brow + wr * 64;
  const int bcol0 = bcol + wc * 64;
  float* rp = rpart + (size_t)(bx * 2 + wc) * BQ;
  float* cp = cpart + (size_t)(by * 2 + wr) * BQ;
  float colp[4] = {0.f, 0.f, 0.f, 0.f};
#pragma unroll
  for (int mi = 0; mi < 4; ++mi) {
    float rowp[4] = {0.f, 0.f, 0.f, 0.f};
#pragma unroll
    for (int ni = 0; ni < 4; ++ni) {
      const f32x4 v = acc[mi][ni];
#pragma unroll
      for (int r = 0; r < 4; ++r) {
        const float sv = v[r] * inv_tau;
        const float e = __expf(sv);
        const int gr = arow0 + mi * 16 + lrow * 4 + r;
        const int gc = bcol0 + ni * 16 + lcol;
        if (gr == gc) diag[gr] = sv;
        rowp[r] += e;
        colp[ni] += e;
      }
    }
#pragma unroll
    for (int r = 0; r < 4; ++r) {
      float x = rowp[r];
      x += __shfl_xor(x, 1);
      x += __shfl_xor(x, 2);
      x += __shfl_xor(x, 4);
      x += __shfl_xor(x, 8);
      if (lcol == 0) rp[arow0 + mi * 16 + lrow * 4 + r] = x;
    }
  }
#pragma unroll
  for (int ni = 0; ni < 4; ++ni) {
    float x = colp[ni];
    x += __shfl_xor(x, 16);
    x += __shfl_xor(x, 32);
    if (lrow == 0) cp[bcol0 + ni * 16 + lcol] = x;
  }
}

// ---------------- finalize: re-scan counts, reduce partials ----------------
__global__ __launch_bounds__(1024) void finalize_kernel(
    const int* __restrict__ counts, const float* __restrict__ diag,
    const float* __restrict__ rpart, const float* __restrict__ cpart,
    const float* __restrict__ npart, float* __restrict__ out) {
  __shared__ int wtot[16];
  __shared__ float wsum[16];
  const int t = threadIdx.x, wid = t >> 6, lane = t & 63;

  const int4 c = reinterpret_cast<const int4*>(counts)[t];  // queries 4t..4t+3
  const int s = c.x + c.y + c.z + c.w;
  int x = s;
#pragma unroll
  for (int off = 1; off < 64; off <<= 1) {
    const int v = __shfl_up(x, off);
    if (lane >= off) x += v;
  }
  if (lane == 63) wtot[wid] = x;
  __syncthreads();
  int base = 0;
  for (int w = 0; w < wid; ++w) base += wtot[w];
  base += x - s;  // exclusive offset for query 4t

  float r0 = 0, r1 = 0, r2 = 0, r3 = 0, c0 = 0, c1 = 0, c2 = 0, c3 = 0;
#pragma unroll 8
  for (int k = 0; k < 64; ++k) {
    const float4 rv = reinterpret_cast<const float4*>(rpart)[k * 1024 + t];
    const float4 cv = reinterpret_cast<const float4*>(cpart)[k * 1024 + t];
    r0 += rv.x; r1 += rv.y; r2 += rv.z; r3 += rv.w;
    c0 += cv.x; c1 += cv.y; c2 += cv.z; c3 += cv.w;
  }
  const float4 dg = reinterpret_cast<const float4*>(diag)[t];

  float n0 = 0, n1 = 0, n2 = 0, n3 = 0;
  {
    int e = base;
    for (int i = 0; i < c.x; ++i) n0 += npart[e + i];
    e += c.x;
    for (int i = 0; i < c.y; ++i) n1 += npart[e + i];
    e += c.y;
    for (int i = 0; i < c.z; ++i) n2 += npart[e + i];
    e += c.z;
    for (int i = 0; i < c.w; ++i) n3 += npart[e + i];
  }

  float v = __logf(r0 + n0) + __logf(c0) - 2.f * dg.x
          + __logf(r1 + n1) + __logf(c1) - 2.f * dg.y
          + __logf(r2 + n2) + __logf(c2) - 2.f * dg.z
          + __logf(r3 + n3) + __logf(c3) - 2.f * dg.w;
  v += __shfl_xor(v, 1);
  v += __shfl_xor(v, 2);
  v += __shfl_xor(v, 4);
  v += __shfl_xor(v, 8);
  v += __shfl_xor(v, 16);
  v += __shfl_xor(v, 32);
  if (lane == 0) wsum[wid] = v;
  __syncthreads();
  if (wid == 0) {
    float y = (lane < 16) ? wsum[lane] : 0.f;
    y += __shfl_xor(y, 1);
    y += __shfl_xor(y, 2);
    y += __shfl_xor(y, 4);
    y += __shfl_xor(y, 8);
    if (lane == 0) out[0] = y / (2.0f * BQ);
  }
}

extern "C" void kernel_launch(void* const* d_in, const int* in_sizes, int n_in,
                              void* d_out, int out_size, void* d_ws, size_t ws_size,
                              hipStream_t stream) {
  const float* q      = (const float*)d_in[0];
  const float* p      = (const float*)d_in[1];
  const float* n_emb  = (const float*)d_in[2];
  const int*   counts = (const int*)d_in[3];
  const float* logtau = (const float*)d_in[4];
  float* out = (float*)d_out;

  float* ws    = (float*)d_ws;
  float* diag  = ws;                       // [4096]
  float* rpart = ws + BQ;                  // [64*4096]
  float* cpart = rpart + 64 * BQ;          // [64*4096]
  float* npart = cpart + 64 * BQ;          // [32768]

  simneg_kernel<<<2048, 256, 0, stream>>>(q, p, n_emb, counts, logtau,
                                          diag, rpart, cpart, npart);
  finalize_kernel<<<1, 1024, 0, stream>>>(counts, diag, rpart, cpart, npart, out);
}

// Round 6
// 132.560 us; speedup vs baseline: 1.2933x; 1.2933x over previous
//
#include <hip/hip_runtime.h>
#include <math.h>

#define BQ 4096
#define DD 256
#define NNEG 32768

typedef __bf16 bf16x8 __attribute__((ext_vector_type(8)));
typedef float f32x4 __attribute__((ext_vector_type(4)));

typedef const __attribute__((address_space(1))) void GvPtr;
typedef __attribute__((address_space(3))) void LdsPtr;

// ws layout:
//   float row_sum[4096] | float col_sum[4096] | float diag[4096] |
//   int owner[32768] | ushort qb[4096*256] | ushort pb[4096*256]

__device__ __forceinline__ float get_inv_tau(const float* __restrict__ lt) {
  float tau = __expf(lt[0]);
  tau = fminf(fmaxf(tau, 1e-4f), 1.0f);
  return 1.0f / tau;
}

__device__ __forceinline__ unsigned int f2bf(float f) {
  unsigned int u = __float_as_uint(f);
  u += 0x7FFFu + ((u >> 16) & 1u);  // RNE
  return u >> 16;
}

// ---------- prep: blocks 0..1023 convert q,p -> bf16; block 1024 zeroes
// row/col sums + scans counts + scatters owner map ----------
__global__ __launch_bounds__(256) void prep_kernel(
    const float* __restrict__ q, const float* __restrict__ p,
    const int* __restrict__ counts,
    ushort* __restrict__ qb, ushort* __restrict__ pb,
    int* __restrict__ owner, float* __restrict__ rowcol /* 8192 floats */) {
  __shared__ int wtot[4];
  const int t = threadIdx.x;
  if (blockIdx.x < 1024) {
    const int i = blockIdx.x * 256 + t;  // 8 elems each
    const int half = (BQ * DD) / 8;      // 131072
    const float* src = (i < half) ? q : p;
    ushort* dst = (i < half) ? qb : pb;
    const int idx = (i < half) ? i : (i - half);
    const float4 a = *reinterpret_cast<const float4*>(&src[idx * 8]);
    const float4 b = *reinterpret_cast<const float4*>(&src[idx * 8 + 4]);
    uint4 o;
    o.x = f2bf(a.x) | (f2bf(a.y) << 16);
    o.y = f2bf(a.z) | (f2bf(a.w) << 16);
    o.z = f2bf(b.x) | (f2bf(b.y) << 16);
    o.w = f2bf(b.z) | (f2bf(b.w) << 16);
    *reinterpret_cast<uint4*>(&dst[idx * 8]) = o;
    return;
  }
  // ---- scan + zero block ----
  const int wid = t >> 6, lane = t & 63;
  const float4 z = {0.f, 0.f, 0.f, 0.f};
#pragma unroll
  for (int i = 0; i < 8; ++i) reinterpret_cast<float4*>(rowcol)[t * 8 + i] = z;

  int cl[16];
  int s = 0;
#pragma unroll
  for (int i = 0; i < 4; ++i) {
    const int4 c = reinterpret_cast<const int4*>(counts)[t * 4 + i];
    cl[4 * i + 0] = c.x; cl[4 * i + 1] = c.y; cl[4 * i + 2] = c.z; cl[4 * i + 3] = c.w;
    s += c.x + c.y + c.z + c.w;
  }
  int x = s;
#pragma unroll
  for (int off = 1; off < 64; off <<= 1) {
    const int v = __shfl_up(x, off);
    if (lane >= off) x += v;
  }
  if (lane == 63) wtot[wid] = x;
  __syncthreads();
  int base = 0;
  for (int w = 0; w < wid; ++w) base += wtot[w];
  int running = base + x - s;  // exclusive prefix for this thread's 16 queries
#pragma unroll
  for (int k = 0; k < 16; ++k) {
    const int qi = 16 * t + k;
    for (int e = 0; e < cl[k]; ++e) owner[running + e] = qi;
    running += cl[k];
  }
}

// ---------- main: 1024 blocks (exactly 4/CU resident). Each block:
//   sim 128x128 tile (4 waves, BK=32 dbuf, global_load_lds, fused epilogue)
//   then its own 32 negatives (32 groups x 8 lanes). ----------
__global__ __launch_bounds__(256) void main_kernel(
    const ushort* __restrict__ qb, const ushort* __restrict__ pb,
    const float* __restrict__ q, const float* __restrict__ n_emb,
    const int* __restrict__ owner, const float* __restrict__ logtau,
    float* __restrict__ row_sum, float* __restrict__ col_sum,
    float* __restrict__ diag) {
  __shared__ ushort As[2][128 * 32];
  __shared__ ushort Bs[2][128 * 32];

  const int tid = threadIdx.x;
  const int bid = (int)blockIdx.x;
  const float inv_tau = get_inv_tau(logtau);

  const int lane = tid & 63;
  const int wv = tid >> 6;
  const int wr = wv >> 1, wc = wv & 1;
  const int lrow = lane >> 4;   // 0..3
  const int lcol = lane & 15;   // 0..15

  // XCD-aware swizzle (1024 blocks, bijective: 8 XCDs x 128)
  const int swz = (bid & 7) * 128 + (bid >> 3);
  const int bx = swz & 31, by = swz >> 5;
  const int brow = by * 128, bcol = bx * 128;

  // staging coords: thread covers 16B at row (i*64 + sr), bf16 col sc
  const int sr = tid >> 2;        // 0..63
  const int sc = (tid & 3) * 8;   // 0,8,16,24

  f32x4 acc[4][4];
#pragma unroll
  for (int i = 0; i < 4; ++i)
#pragma unroll
    for (int j = 0; j < 4; ++j) acc[i][j] = (f32x4){0.f, 0.f, 0.f, 0.f};

#define STAGE(buf, k0)                                                          \
  {                                                                             \
    _Pragma("unroll")                                                           \
    for (int i = 0; i < 2; ++i) {                                               \
      const ushort* ga = qb + (size_t)(brow + i * 64 + sr) * DD + (k0) + sc;    \
      __builtin_amdgcn_global_load_lds((GvPtr*)ga,                              \
          (LdsPtr*)(&As[buf][0] + i * 2048 + tid * 8), 16, 0, 0);               \
      const ushort* gb = pb + (size_t)(bcol + i * 64 + sr) * DD + (k0) + sc;    \
      __builtin_amdgcn_global_load_lds((GvPtr*)gb,                              \
          (LdsPtr*)(&Bs[buf][0] + i * 2048 + tid * 8), 16, 0, 0);               \
    }                                                                           \
  }

  STAGE(0, 0);
  __syncthreads();

#pragma unroll
  for (int t = 0; t < 8; ++t) {
    if (t < 7) STAGE((t + 1) & 1, (t + 1) * 32);
    const ushort* lA = &As[t & 1][0];
    const ushort* lB = &Bs[t & 1][0];
    bf16x8 a[4], b[4];
#pragma unroll
    for (int m = 0; m < 4; ++m)
      a[m] = *reinterpret_cast<const bf16x8*>(lA + (wr * 64 + m * 16 + lcol) * 32 + lrow * 8);
#pragma unroll
    for (int n = 0; n < 4; ++n)
      b[n] = *reinterpret_cast<const bf16x8*>(lB + (wc * 64 + n * 16 + lcol) * 32 + lrow * 8);
#pragma unroll
    for (int m = 0; m < 4; ++m)
#pragma unroll
      for (int n = 0; n < 4; ++n)
        acc[m][n] = __builtin_amdgcn_mfma_f32_16x16x32_bf16(a[m], b[n], acc[m][n], 0, 0, 0);
    __syncthreads();
  }
#undef STAGE

  // epilogue: exp + row/col reductions + diag
  const int arow0 = brow + wr * 64;
  const int bcol0 = bcol + wc * 64;
  float colp[4] = {0.f, 0.f, 0.f, 0.f};
#pragma unroll
  for (int mi = 0; mi < 4; ++mi) {
    float rowp[4] = {0.f, 0.f, 0.f, 0.f};
#pragma unroll
    for (int ni = 0; ni < 4; ++ni) {
      const f32x4 v = acc[mi][ni];
#pragma unroll
      for (int r = 0; r < 4; ++r) {
        const float sv = v[r] * inv_tau;
        const float e = __expf(sv);
        const int gr = arow0 + mi * 16 + lrow * 4 + r;
        const int gc = bcol0 + ni * 16 + lcol;
        if (gr == gc) diag[gr] = sv;
        rowp[r] += e;
        colp[ni] += e;
      }
    }
#pragma unroll
    for (int r = 0; r < 4; ++r) {
      float x = rowp[r];
      x += __shfl_xor(x, 1);
      x += __shfl_xor(x, 2);
      x += __shfl_xor(x, 4);
      x += __shfl_xor(x, 8);
      if (lcol == 0) atomicAdd(&row_sum[arow0 + mi * 16 + lrow * 4 + r], x);
    }
  }
#pragma unroll
  for (int ni = 0; ni < 4; ++ni) {
    float x = colp[ni];
    x += __shfl_xor(x, 16);
    x += __shfl_xor(x, 32);
    if (lrow == 0) atomicAdd(&col_sum[bcol0 + ni * 16 + lcol], x);
  }

  // ---- this block's 32 negatives: group g (8 lanes) handles negative j ----
  const int g = tid >> 3;           // 0..31
  const int sl = tid & 7;           // 0..7
  const int j = bid * 32 + g;
  const int ow = owner[j];
  const float4* nrow = reinterpret_cast<const float4*>(n_emb + (size_t)j * DD);
  const float4* qrow = reinterpret_cast<const float4*>(q + (size_t)ow * DD);
  float d0 = 0.f, d1 = 0.f;
#pragma unroll
  for (int t2 = 0; t2 < 8; t2 += 2) {
    const float4 n0 = nrow[sl + 8 * t2];
    const float4 q0 = qrow[sl + 8 * t2];
    const float4 n1 = nrow[sl + 8 * (t2 + 1)];
    const float4 q1 = qrow[sl + 8 * (t2 + 1)];
    d0 += q0.x * n0.x + q0.y * n0.y + q0.z * n0.z + q0.w * n0.w;
    d1 += q1.x * n1.x + q1.y * n1.y + q1.z * n1.z + q1.w * n1.w;
  }
  float d = d0 + d1;
  d += __shfl_xor(d, 1);
  d += __shfl_xor(d, 2);
  d += __shfl_xor(d, 4);
  if (sl == 0) atomicAdd(&row_sum[ow], __expf(d * inv_tau));
}

// ---------- finalize: 1 block, reads 48 KB ----------
__global__ __launch_bounds__(1024) void finalize_kernel(
    const float* __restrict__ row_sum, const float* __restrict__ col_sum,
    const float* __restrict__ diag, float* __restrict__ out) {
  __shared__ float ws[16];
  const int t = threadIdx.x;
  const int wid = t >> 6, lane = t & 63;
  const float4 r = reinterpret_cast<const float4*>(row_sum)[t];
  const float4 c = reinterpret_cast<const float4*>(col_sum)[t];
  const float4 d = reinterpret_cast<const float4*>(diag)[t];
  float v = __logf(r.x) + __logf(r.y) + __logf(r.z) + __logf(r.w)
          + __logf(c.x) + __logf(c.y) + __logf(c.z) + __logf(c.w)
          - 2.f * (d.x + d.y + d.z + d.w);
  v += __shfl_xor(v, 1);
  v += __shfl_xor(v, 2);
  v += __shfl_xor(v, 4);
  v += __shfl_xor(v, 8);
  v += __shfl_xor(v, 16);
  v += __shfl_xor(v, 32);
  if (lane == 0) ws[wid] = v;
  __syncthreads();
  if (wid == 0) {
    float x = (lane < 16) ? ws[lane] : 0.f;
    x += __shfl_xor(x, 1);
    x += __shfl_xor(x, 2);
    x += __shfl_xor(x, 4);
    x += __shfl_xor(x, 8);
    if (lane == 0) out[0] = x / (2.0f * BQ);
  }
}

extern "C" void kernel_launch(void* const* d_in, const int* in_sizes, int n_in,
                              void* d_out, int out_size, void* d_ws, size_t ws_size,
                              hipStream_t stream) {
  const float* q      = (const float*)d_in[0];
  const float* p      = (const float*)d_in[1];
  const float* n_emb  = (const float*)d_in[2];
  const int*   counts = (const int*)d_in[3];
  const float* logtau = (const float*)d_in[4];
  float* out = (float*)d_out;

  float* ws      = (float*)d_ws;
  float* row_sum = ws;            // [4096]
  float* col_sum = ws + BQ;       // [4096]
  float* diag    = ws + 2 * BQ;   // [4096]
  int*   owner   = (int*)(ws + 3 * BQ);           // [32768]
  ushort* qb     = (ushort*)(owner + NNEG);       // [4096*256]
  ushort* pb     = qb + (size_t)BQ * DD;          // [4096*256]

  prep_kernel<<<1025, 256, 0, stream>>>(q, p, counts, qb, pb, owner, row_sum);
  main_kernel<<<1024, 256, 0, stream>>>(qb, pb, q, n_emb, owner, logtau,
                                        row_sum, col_sum, diag);
  finalize_kernel<<<1, 1024, 0, stream>>>(row_sum, col_sum, diag, out);
}